// Round 2
// baseline (207.463 us; speedup 1.0000x reference)
//
#include <hip/hip_runtime.h>
#include <hip/hip_bf16.h>

// Problem constants (fixed by setup_inputs)
#define NINST    128
#define CIN      8
#define HH       100
#define WW       152
#define HWSZ     (HH * WW)          // 15200
#define OHGT     200
#define OWID     304
#define TYO      20                  // output rows per block
#define NTILES   10                  // OHGT / TYO
#define ROWS     12                  // input rows needed per strip (10 + 2 halo)
#define PPI      419                 // params per instance: 169 body + 169 edge + 81 fused
#define OUT_PER_INST (OHGT * OWID)   // 60800

// Per-instance param layout (row of 419 floats):
//  body:  w1[8][10]@0  w2[8][8]@80  w3[8]@144  b1[8]@152 b2[8]@160 b3@168
//  edge:  same +169
//  fused: wf1[8][8]@338 wf2[8]@402 bf1[8]@410 bf2@418

__global__ __launch_bounds__(256) void dmh_fused_kernel(
    const float* __restrict__ fbody,      // [2][8][H][W]
    const float* __restrict__ fedge,      // [2][8][H][W]
    const float* __restrict__ params,     // [128][419]
    const float* __restrict__ locs,       // [128][2]
    const float* __restrict__ soi_tab,    // [5]
    const int*   __restrict__ im_inds,    // [128]
    const int*   __restrict__ fpn_levels, // [128]
    float* __restrict__ out,              // [3][n_inst][200][304], fp32
    int n_inst)
{
    const int n   = blockIdx.x;   // instance
    const int t   = blockIdx.y;   // row-strip tile
    const int tid = threadIdx.x;

    __shared__ float slog[3][ROWS][WW];   // logits for body/edge/fused, input-res tile

    // Block-uniform instance scalars (scalar loads)
    const float* __restrict__ p = params + (size_t)n * PPI;
    const int   im  = im_inds[n];
    const float soi = soi_tab[fpn_levels[n]];
    const float inv_soi = 1.0f / soi;
    const float locx = locs[2 * n];
    const float locy = locs[2 * n + 1];
    // rel_x(c) = (locx - (c*8+4))/soi = sx - c*k8 ; rel_y(r) likewise
    const float sx = (locx - 4.0f) * inv_soi;
    const float sy = (locy - 4.0f) * inv_soi;
    const float k8 = 8.0f * inv_soi;

    const int rbase = max(10 * t - 1, 0);  // first input row of this strip's halo
    const float* __restrict__ fb_base = fbody + (size_t)im * CIN * HWSZ;
    const float* __restrict__ fe_base = fedge + (size_t)im * CIN * HWSZ;

    // ---------------- Phase 1: per-pixel dynamic MLPs -> LDS logits -------------
    for (int pi = tid; pi < ROWS * WW; pi += 256) {
        const int rl = pi / WW;
        const int c  = pi - rl * WW;
        const int r  = min(rbase + rl, HH - 1);   // clamp (edge pad) keeps indexing branch-free

        const float dx = sx - (float)c * k8;
        const float dy = sy - (float)r * k8;

        const float* fb = fb_base + r * WW + c;
        const float* fe = fe_base + r * WW + c;

        float ib[10], ie[10];
        ib[0] = dx; ib[1] = dy;
        ie[0] = dx; ie[1] = dy;
        #pragma unroll
        for (int k = 0; k < 8; ++k) {
            ib[k + 2] = fb[k * HWSZ];   // coalesced across lanes within each channel
            ie[k + 2] = fe[k * HWSZ];
        }

        // Layer 1 (10 -> 8) + ReLU, body & edge
        float h1b[8], h1e[8];
        #pragma unroll
        for (int o = 0; o < 8; ++o) {
            float ab = p[152 + o];
            float ae = p[169 + 152 + o];
            #pragma unroll
            for (int k = 0; k < 10; ++k) {
                ab = fmaf(p[o * 10 + k],       ib[k], ab);
                ae = fmaf(p[169 + o * 10 + k], ie[k], ae);
            }
            h1b[o] = fmaxf(ab, 0.0f);
            h1e[o] = fmaxf(ae, 0.0f);
        }

        // Layer 2 (8 -> 8) + ReLU, body & edge
        float h2b[8], h2e[8], h2s[8];
        #pragma unroll
        for (int o = 0; o < 8; ++o) {
            float ab = p[160 + o];
            float ae = p[169 + 160 + o];
            #pragma unroll
            for (int k = 0; k < 8; ++k) {
                ab = fmaf(p[80 + o * 8 + k],       h1b[k], ab);
                ae = fmaf(p[169 + 80 + o * 8 + k], h1e[k], ae);
            }
            h2b[o] = fmaxf(ab, 0.0f);
            h2e[o] = fmaxf(ae, 0.0f);
        }
        #pragma unroll
        for (int k = 0; k < 8; ++k) h2s[k] = h2b[k] + h2e[k];

        // Fused head layer 1 (8 -> 8) + ReLU on (h2b + h2e)
        float hf[8];
        #pragma unroll
        for (int o = 0; o < 8; ++o) {
            float af = p[410 + o];
            #pragma unroll
            for (int k = 0; k < 8; ++k)
                af = fmaf(p[338 + o * 8 + k], h2s[k], af);
            hf[o] = fmaxf(af, 0.0f);
        }

        // Final logits (8 -> 1), all three heads
        float lb = p[168];
        float le = p[169 + 168];
        float lf = p[418];
        #pragma unroll
        for (int k = 0; k < 8; ++k) {
            lb = fmaf(p[144 + k],       h2b[k], lb);
            le = fmaf(p[169 + 144 + k], h2e[k], le);
            lf = fmaf(p[402 + k],       hf[k],  lf);
        }

        slog[0][rl][c] = lb;
        slog[1][rl][c] = le;
        slog[2][rl][c] = lf;
    }
    __syncthreads();

    // -------- Phase 2: aligned_bilinear x2 + sigmoid + fp32 store ---------------
    // out[y][x] = bilerp at (i,j) = (max(y-1,0), max(x-1,0)) in the align_corners
    // grid: r0=i>>1, fy=(i&1)*0.5 (rows clamped to 99), c0=j>>1, fx=(j&1)*0.5
    // (cols clamped to 151).
    const int    y0    = t * TYO;
    const size_t obase = (size_t)n * OUT_PER_INST;
    const size_t head_stride = (size_t)n_inst * OUT_PER_INST;

    for (int q = tid; q < 3 * TYO * OWID; q += 256) {
        const int h   = q / (TYO * OWID);
        const int rem = q - h * (TYO * OWID);
        const int ly  = rem / OWID;
        const int x   = rem - ly * OWID;
        const int y   = y0 + ly;

        const int i = max(y - 1, 0);
        const int j = max(x - 1, 0);
        const int r0 = i >> 1;                 // >= rbase by construction
        const int c0 = j >> 1;
        const float fy = (i & 1) ? 0.5f : 0.0f;
        const float fx = (j & 1) ? 0.5f : 0.0f;

        const int r0l = r0 - rbase;
        const int r1l = min(r0 + 1, HH - 1) - rbase;
        const int c1  = min(c0 + 1, WW - 1);

        const float v00 = slog[h][r0l][c0];
        const float v01 = slog[h][r0l][c1];
        const float v10 = slog[h][r1l][c0];
        const float v11 = slog[h][r1l][c1];

        const float v0 = v00 + fx * (v01 - v00);
        const float v1 = v10 + fx * (v11 - v10);
        const float v  = v0  + fy * (v1  - v0);

        const float s = 1.0f / (1.0f + __expf(-v));
        out[(size_t)h * head_stride + obase + (size_t)y * OWID + x] = s;
    }
}

extern "C" void kernel_launch(void* const* d_in, const int* in_sizes, int n_in,
                              void* d_out, int out_size, void* d_ws, size_t ws_size,
                              hipStream_t stream) {
    const float* fbody   = (const float*)d_in[0];
    const float* fedge   = (const float*)d_in[1];
    const float* params  = (const float*)d_in[2];
    const float* locs    = (const float*)d_in[3];
    const float* soi     = (const float*)d_in[4];
    const int*   im_inds = (const int*)d_in[5];
    const int*   fpn     = (const int*)d_in[6];
    // d_in[7] = mask_feat_stride (always 8 per setup_inputs; factor=2 baked in)

    const int n_inst = in_sizes[5];  // 128

    dim3 grid(n_inst, NTILES);
    dmh_fused_kernel<<<grid, dim3(256), 0, stream>>>(
        fbody, fedge, params, locs, soi, im_inds, fpn,
        (float*)d_out, n_inst);
}

// Round 3
// 59.555 us; speedup vs baseline: 3.4836x; 3.4836x over previous
//
#include <hip/hip_runtime.h>
#include <hip/hip_bf16.h>

// Problem constants (fixed by setup_inputs)
#define CIN      8
#define HH       100
#define WW       152
#define HWSZ     (HH * WW)          // 15200
#define OHGT     200
#define OWID     304
#define PPI      419                 // params per instance: 169 body + 169 edge + 81 fused
#define OUT_PER_INST (OHGT * OWID)   // 60800

// Per-instance param layout (row of 419 floats):
//  body:  w1[8][10]@0  w2[8][8]@80  w3[8]@144  b1[8]@152 b2[8]@160 b3@168
//  edge:  same +169
//  fused: wf1[8][8]@338 wf2[8]@402 bf1[8]@410 bf2@418

// ------------------------------------------------------------------------
// K1: per-pixel dynamic MLPs -> logits[3][n_inst][100][152] (fp32, in d_ws)
// ONE pixel per thread, NO pixel loop: every weight s_load is single-use,
// so nothing is loop-invariant -> no SGPR hoist-and-spill.
// ------------------------------------------------------------------------
__global__ __launch_bounds__(256) void dmh_mlp_kernel(
    const float* __restrict__ fbody,      // [2][8][H][W]
    const float* __restrict__ fedge,      // [2][8][H][W]
    const float* __restrict__ params,     // [n_inst][419]
    const float* __restrict__ locs,       // [n_inst][2]
    const float* __restrict__ soi_tab,    // [5]
    const int*   __restrict__ im_inds,    // [n_inst]
    const int*   __restrict__ fpn_levels, // [n_inst]
    float* __restrict__ logits,           // [3][n_inst][HWSZ]
    int n_inst)
{
    const int n  = blockIdx.y;
    const int px = blockIdx.x * 256 + threadIdx.x;
    if (px >= HWSZ) return;

    const float* __restrict__ p = params + (size_t)n * PPI;
    const int   im      = im_inds[n];
    const float inv_soi = 1.0f / soi_tab[fpn_levels[n]];
    const float sx = (locs[2 * n]     - 4.0f) * inv_soi;
    const float sy = (locs[2 * n + 1] - 4.0f) * inv_soi;
    const float k8 = 8.0f * inv_soi;

    const int r = px / WW;
    const int c = px - r * WW;
    const float dx = sx - (float)c * k8;
    const float dy = sy - (float)r * k8;

    const float* __restrict__ fb = fbody + (size_t)im * CIN * HWSZ + px;
    const float* __restrict__ fe = fedge + (size_t)im * CIN * HWSZ + px;

    float in[10], h1[8];

    // ---------------- body head ----------------
    in[0] = dx; in[1] = dy;
    #pragma unroll
    for (int k = 0; k < 8; ++k) in[k + 2] = fb[k * HWSZ];

    #pragma unroll
    for (int o = 0; o < 8; ++o) {
        float a = p[152 + o];
        #pragma unroll
        for (int k = 0; k < 10; ++k) a = fmaf(p[o * 10 + k], in[k], a);
        h1[o] = fmaxf(a, 0.0f);
    }
    float h2b[8];
    #pragma unroll
    for (int o = 0; o < 8; ++o) {
        float a = p[160 + o];
        #pragma unroll
        for (int k = 0; k < 8; ++k) a = fmaf(p[80 + o * 8 + k], h1[k], a);
        h2b[o] = fmaxf(a, 0.0f);
    }
    float lb = p[168];
    #pragma unroll
    for (int k = 0; k < 8; ++k) lb = fmaf(p[144 + k], h2b[k], lb);

    // ---------------- edge head (reuses in/h1) ----------------
    #pragma unroll
    for (int k = 0; k < 8; ++k) in[k + 2] = fe[k * HWSZ];

    #pragma unroll
    for (int o = 0; o < 8; ++o) {
        float a = p[169 + 152 + o];
        #pragma unroll
        for (int k = 0; k < 10; ++k) a = fmaf(p[169 + o * 10 + k], in[k], a);
        h1[o] = fmaxf(a, 0.0f);
    }
    float h2e[8];
    #pragma unroll
    for (int o = 0; o < 8; ++o) {
        float a = p[169 + 160 + o];
        #pragma unroll
        for (int k = 0; k < 8; ++k) a = fmaf(p[169 + 80 + o * 8 + k], h1[k], a);
        h2e[o] = fmaxf(a, 0.0f);
    }
    float le = p[169 + 168];
    #pragma unroll
    for (int k = 0; k < 8; ++k) le = fmaf(p[169 + 144 + k], h2e[k], le);

    // ---------------- fused head on relu(h2b)+relu(h2e) ----------------
    float hs[8];
    #pragma unroll
    for (int k = 0; k < 8; ++k) hs[k] = h2b[k] + h2e[k];

    float hf[8];
    #pragma unroll
    for (int o = 0; o < 8; ++o) {
        float a = p[410 + o];
        #pragma unroll
        for (int k = 0; k < 8; ++k) a = fmaf(p[338 + o * 8 + k], hs[k], a);
        hf[o] = fmaxf(a, 0.0f);
    }
    float lf = p[418];
    #pragma unroll
    for (int k = 0; k < 8; ++k) lf = fmaf(p[402 + k], hf[k], lf);

    const size_t hstride = (size_t)n_inst * HWSZ;
    float* lg = logits + (size_t)n * HWSZ + px;
    lg[0]           = lb;
    lg[hstride]     = le;
    lg[2 * hstride] = lf;
}

// ------------------------------------------------------------------------
// K2: aligned_bilinear x2 + sigmoid + fp32 store.
// Thread <-> (h*n_inst+n, r, q). 2 rows x 4 cols of output per thread from
// 6 logit loads; float4 stores. Closed form: out[y][x] samples logit grid at
// (i,j)=(max(y-1,0),max(x-1,0)); r0=i>>1, fy=(i&1)/2; c0=j>>1, fx=(j&1)/2.
//   row A: y=2r+1 (fy=0, row r);  row B: y=2r+2 (fy=1/2, rows r,r+1)
//   y=0 == y=1 (written when r==0); row B skipped at r==99.
//   x=4q: (L[2q-1]+L[2q])/2   x=4q+1: L[2q]
//   x=4q+2: (L[2q]+L[2q+1])/2 x=4q+3: L[2q+1]   (cols clamped to [0,151])
// ------------------------------------------------------------------------
__global__ __launch_bounds__(256) void dmh_upsample_kernel(
    const float* __restrict__ logits,   // [3*n_inst][HWSZ]
    float* __restrict__ out)            // [3*n_inst][200][304]
{
    int idx = blockIdx.x * 256 + threadIdx.x;   // 3*n_inst*100*76 threads
    const int q = idx % 76;  idx /= 76;
    const int r = idx % HH;  idx /= HH;         // idx = h*n_inst + n

    const float* __restrict__ L = logits + (size_t)idx * HWSZ + r * WW;
    float* __restrict__ O = out + (size_t)idx * OUT_PER_INST;

    const int cm = max(2 * q - 1, 0);
    const int c0 = 2 * q;
    const int cp = min(2 * q + 1, WW - 1);
    const int rpOff = (r < HH - 1) ? WW : 0;    // clamp row r+1

    const float Lm0 = L[cm],         L00 = L[c0],         Lp0 = L[cp];
    const float Lm1 = L[cm + rpOff], L01 = L[c0 + rpOff], Lp1 = L[cp + rpOff];

    // row A (y = 2r+1)
    const float a0 = 0.5f * (Lm0 + L00);
    const float a1 = L00;
    const float a2 = 0.5f * (L00 + Lp0);
    const float a3 = Lp0;
    // row B (y = 2r+2): average rows first
    const float m  = 0.5f * (Lm0 + Lm1);
    const float z  = 0.5f * (L00 + L01);
    const float pz = 0.5f * (Lp0 + Lp1);
    const float b0 = 0.5f * (m + z);
    const float b1 = z;
    const float b2 = 0.5f * (z + pz);
    const float b3 = pz;

    float4 A, B;
    A.x = 1.0f / (1.0f + __expf(-a0));
    A.y = 1.0f / (1.0f + __expf(-a1));
    A.z = 1.0f / (1.0f + __expf(-a2));
    A.w = 1.0f / (1.0f + __expf(-a3));
    B.x = 1.0f / (1.0f + __expf(-b0));
    B.y = 1.0f / (1.0f + __expf(-b1));
    B.z = 1.0f / (1.0f + __expf(-b2));
    B.w = 1.0f / (1.0f + __expf(-b3));

    const int xq = 4 * q;
    *(float4*)(O + (size_t)(2 * r + 1) * OWID + xq) = A;          // y = 2r+1
    if (r == 0)
        *(float4*)(O + xq) = A;                                    // y = 0 (== y=1)
    if (r < HH - 1)
        *(float4*)(O + (size_t)(2 * r + 2) * OWID + xq) = B;      // y = 2r+2
}

// ------------------------------------------------------------------------
// Fallback (correct, slower): original fused kernel, used only if d_ws is
// too small for the logits intermediate.
// ------------------------------------------------------------------------
#define TYO 20
#define NTILES 10
#define ROWS 12
__global__ __launch_bounds__(256) void dmh_fused_kernel(
    const float* __restrict__ fbody, const float* __restrict__ fedge,
    const float* __restrict__ params, const float* __restrict__ locs,
    const float* __restrict__ soi_tab, const int* __restrict__ im_inds,
    const int* __restrict__ fpn_levels, float* __restrict__ out, int n_inst)
{
    const int n = blockIdx.x, t = blockIdx.y, tid = threadIdx.x;
    __shared__ float slog[3][ROWS][WW];
    const float* __restrict__ p = params + (size_t)n * PPI;
    const int im = im_inds[n];
    const float inv_soi = 1.0f / soi_tab[fpn_levels[n]];
    const float sx = (locs[2 * n] - 4.0f) * inv_soi;
    const float sy = (locs[2 * n + 1] - 4.0f) * inv_soi;
    const float k8 = 8.0f * inv_soi;
    const int rbase = max(10 * t - 1, 0);
    const float* __restrict__ fb_base = fbody + (size_t)im * CIN * HWSZ;
    const float* __restrict__ fe_base = fedge + (size_t)im * CIN * HWSZ;

    for (int pi = tid; pi < ROWS * WW; pi += 256) {
        const int rl = pi / WW, c = pi - (pi / WW) * WW;
        const int r = min(rbase + rl, HH - 1);
        const float dx = sx - (float)c * k8, dy = sy - (float)r * k8;
        const float* fb = fb_base + r * WW + c;
        const float* fe = fe_base + r * WW + c;
        float ib[10], ie[10];
        ib[0] = dx; ib[1] = dy; ie[0] = dx; ie[1] = dy;
        #pragma unroll
        for (int k = 0; k < 8; ++k) { ib[k+2] = fb[k*HWSZ]; ie[k+2] = fe[k*HWSZ]; }
        float h1b[8], h1e[8];
        #pragma unroll
        for (int o = 0; o < 8; ++o) {
            float ab = p[152+o], ae = p[169+152+o];
            #pragma unroll
            for (int k = 0; k < 10; ++k) { ab = fmaf(p[o*10+k], ib[k], ab); ae = fmaf(p[169+o*10+k], ie[k], ae); }
            h1b[o] = fmaxf(ab, 0.f); h1e[o] = fmaxf(ae, 0.f);
        }
        float h2b[8], h2e[8], h2s[8];
        #pragma unroll
        for (int o = 0; o < 8; ++o) {
            float ab = p[160+o], ae = p[169+160+o];
            #pragma unroll
            for (int k = 0; k < 8; ++k) { ab = fmaf(p[80+o*8+k], h1b[k], ab); ae = fmaf(p[169+80+o*8+k], h1e[k], ae); }
            h2b[o] = fmaxf(ab, 0.f); h2e[o] = fmaxf(ae, 0.f);
        }
        #pragma unroll
        for (int k = 0; k < 8; ++k) h2s[k] = h2b[k] + h2e[k];
        float hf[8];
        #pragma unroll
        for (int o = 0; o < 8; ++o) {
            float af = p[410+o];
            #pragma unroll
            for (int k = 0; k < 8; ++k) af = fmaf(p[338+o*8+k], h2s[k], af);
            hf[o] = fmaxf(af, 0.f);
        }
        float lb = p[168], le = p[169+168], lf = p[418];
        #pragma unroll
        for (int k = 0; k < 8; ++k) { lb = fmaf(p[144+k], h2b[k], lb); le = fmaf(p[169+144+k], h2e[k], le); lf = fmaf(p[402+k], hf[k], lf); }
        slog[0][rl][c] = lb; slog[1][rl][c] = le; slog[2][rl][c] = lf;
    }
    __syncthreads();
    const int y0 = t * TYO;
    const size_t obase = (size_t)n * OUT_PER_INST;
    const size_t head_stride = (size_t)n_inst * OUT_PER_INST;
    for (int qq = tid; qq < 3 * TYO * OWID; qq += 256) {
        const int h = qq / (TYO * OWID);
        const int rem = qq - h * (TYO * OWID);
        const int ly = rem / OWID, x = rem - (rem / OWID) * OWID;
        const int y = y0 + ly;
        const int i = max(y - 1, 0), j = max(x - 1, 0);
        const int r0 = i >> 1, c0 = j >> 1;
        const float fy = (i & 1) ? 0.5f : 0.0f, fx = (j & 1) ? 0.5f : 0.0f;
        const int r0l = r0 - rbase, r1l = min(r0 + 1, HH - 1) - rbase;
        const int c1 = min(c0 + 1, WW - 1);
        const float v00 = slog[h][r0l][c0], v01 = slog[h][r0l][c1];
        const float v10 = slog[h][r1l][c0], v11 = slog[h][r1l][c1];
        const float v0 = v00 + fx * (v01 - v00), v1 = v10 + fx * (v11 - v10);
        const float v = v0 + fy * (v1 - v0);
        out[(size_t)h * head_stride + obase + (size_t)y * OWID + x] = 1.0f / (1.0f + __expf(-v));
    }
}

extern "C" void kernel_launch(void* const* d_in, const int* in_sizes, int n_in,
                              void* d_out, int out_size, void* d_ws, size_t ws_size,
                              hipStream_t stream) {
    const float* fbody   = (const float*)d_in[0];
    const float* fedge   = (const float*)d_in[1];
    const float* params  = (const float*)d_in[2];
    const float* locs    = (const float*)d_in[3];
    const float* soi     = (const float*)d_in[4];
    const int*   im_inds = (const int*)d_in[5];
    const int*   fpn     = (const int*)d_in[6];

    const int n_inst = in_sizes[5];  // 128
    const size_t logits_bytes = (size_t)3 * n_inst * HWSZ * sizeof(float);

    if (ws_size >= logits_bytes) {
        float* logits = (float*)d_ws;
        dim3 g1((HWSZ + 255) / 256, n_inst);
        dmh_mlp_kernel<<<g1, dim3(256), 0, stream>>>(
            fbody, fedge, params, locs, soi, im_inds, fpn, logits, n_inst);
        const int total2 = 3 * n_inst * HH * 76;   // threads: (head,inst) x r x q
        dmh_upsample_kernel<<<dim3(total2 / 256), dim3(256), 0, stream>>>(
            logits, (float*)d_out);
    } else {
        dim3 grid(n_inst, NTILES);
        dmh_fused_kernel<<<grid, dim3(256), 0, stream>>>(
            fbody, fedge, params, locs, soi, im_inds, fpn, (float*)d_out, n_inst);
    }
}